// Round 3
// baseline (571.157 us; speedup 1.0000x reference)
//
#include <hip/hip_runtime.h>
#include <hip/hip_bf16.h>

// fp32 inputs (confirmed r2). Internal pipeline bf16 MFMA.
// Gen identity: w = exp2(max(e,0.2e)) = max(A_i*B_j, C_i*D_j).
// r16 = r13 structure and EXACT r13 Vb layout/read path ([128][136], 272B row
//   stride = natural 4-bank row stagger), but:
//   - single-buffered Vb (34.8KB) + 2-phase epilogue cmb overlay (24KB)
//     -> LDS 35.8KB -> 4 blocks/CU (was 2), launch_bounds(512,8).
//     2 barriers/iter; cross-block interleave hides the bubbles.
//   - staging lane remap vrow=wave*16+(tid&15), vs=(tid>>4)&3: kills the
//     quarter-phase 4-way ds_write conflict (diagonal r+c pattern of r13).
//   - accd (denominator) MFMAs moved before barrier1 (register-only).
//   (r14 no-staging: latency-bound. r15 256B+XOR swizzle: fewer conflicts but
//    slower reads -> both reverted.)
// Mask layout: byte pk[i*512 + g*32 + kb] bits r for j = kb*128 + (g>>2)*32 + (g&3)*8 + r.

typedef unsigned short ushort_t;
typedef __attribute__((ext_vector_type(8))) short bf16x8;
typedef __attribute__((ext_vector_type(4))) float f32x4;

#define LOG2E 1.4426950408889634f

__device__ __forceinline__ ushort_t f2bf(float x) {
    unsigned u = __builtin_bit_cast(unsigned, x);
    u += 0x7FFFu + ((u >> 16) & 1u);   // RNE
    return (ushort_t)(u >> 16);
}

// ---------------- kernel 1: WT[c][k] = W[k][c], 512x512, fp32 -> bf16 ----------------
__global__ __launch_bounds__(256) void transpose_w(const float* __restrict__ W,
                                                   ushort_t* __restrict__ WT) {
    __shared__ ushort_t t[32][33];
    int bx = blockIdx.x & 15, by = blockIdx.x >> 4;
    int tx = threadIdx.x & 31, ty = threadIdx.x >> 5;
#pragma unroll
    for (int i = 0; i < 32; i += 8)
        t[ty + i][tx] = f2bf(W[(by * 32 + ty + i) * 512 + bx * 32 + tx]);
    __syncthreads();
#pragma unroll
    for (int i = 0; i < 32; i += 8)
        WT[(bx * 32 + ty + i) * 512 + by * 32 + tx] = t[tx][ty + i];
}

// -------- kernel 2 (fused): blocks 0-511 = gemm (r8 proven body); 512-1535 = pack ----
__global__ __launch_bounds__(256, 4) void gemm_pack(const ushort_t* __restrict__ WT,
                                                    const float* __restrict__ h,
                                                    const float* __restrict__ a,
                                                    ushort_t* __restrict__ WhT,
                                                    float* __restrict__ expA,
                                                    float* __restrict__ expC,
                                                    float* __restrict__ expB,
                                                    float* __restrict__ expD,
                                                    const int* __restrict__ adj,
                                                    unsigned char* __restrict__ pk) {
    __shared__ __align__(16) ushort_t Al[2][64][72];
    __shared__ __align__(16) ushort_t Bl[2][64][72];
    __shared__ float asrc[64], adst[64];
    __shared__ float sred[2][4][64];
    int tid = threadIdx.x;
    if (blockIdx.x >= 512) {
        // ---------------- pack branch ----------------
        int pbid = blockIdx.x - 512;
        int wv = tid >> 6, lane = tid & 63;
        int row = pbid * 4 + wv;
        const int* ap = adj + (unsigned)row * 4096 + lane;
        unsigned char* pp = pk + (unsigned)row * 512;
        int g = lane;                                 // lanes 0..15 write
        int sv = ((g >> 2) & 1) * 4 + (g & 3);
        int cpar = g >> 3;
#pragma unroll 2
        for (int t = 0; t < 8; t++) {
            unsigned long long m[8];
#pragma unroll
            for (int c8 = 0; c8 < 8; c8++)
                m[c8] = __ballot(ap[(t * 8 + c8) * 64] > 0);
            if (lane < 16) {
                unsigned w = 0;
#pragma unroll
                for (int kq = 0; kq < 4; kq++) {
                    unsigned b = (unsigned)(m[2 * kq + cpar] >> (8 * sv)) & 0xFFu;
                    w |= b << (8 * kq);
                }
                *(unsigned*)(pp + g * 32 + t * 4) = w;
            }
        }
        return;
    }
    // ---------------- gemm branch (r8/r12 proven) ----------------
    int wave = tid >> 6, lane = tid & 63, quad = lane >> 4, nn = lane & 15;
    int mb = blockIdx.x & 7, nb = blockIdx.x >> 3;
    if (tid < 64) {
        asrc[tid] = a[tid] * LOG2E;
        adst[tid] = a[64 + tid] * LOG2E;
    }
    int r = tid >> 2, s0 = tid & 3;
    const ushort_t* Ag = WT + (unsigned)((mb * 64 + r) * 512 + s0 * 8);
    const float* Bg = h + (unsigned)((nb * 64 + r) * 512 + s0 * 8);
    bf16x8 pA0 = *(const bf16x8*)(Ag);
    bf16x8 pA1 = *(const bf16x8*)(Ag + 32);
    float4 pb0 = *(const float4*)(Bg);
    float4 pb1 = *(const float4*)(Bg + 4);
    float4 pb2 = *(const float4*)(Bg + 32);
    float4 pb3 = *(const float4*)(Bg + 36);
    f32x4 acc[4] = {};
#pragma unroll 2
    for (int t = 0; t < 8; t++) {
        int cb = t & 1;
        *(bf16x8*)&Al[cb][r][s0 * 8] = pA0;
        *(bf16x8*)&Al[cb][r][s0 * 8 + 32] = pA1;
        bf16x8 bv;
        bv[0] = (short)f2bf(pb0.x); bv[1] = (short)f2bf(pb0.y);
        bv[2] = (short)f2bf(pb0.z); bv[3] = (short)f2bf(pb0.w);
        bv[4] = (short)f2bf(pb1.x); bv[5] = (short)f2bf(pb1.y);
        bv[6] = (short)f2bf(pb1.z); bv[7] = (short)f2bf(pb1.w);
        *(bf16x8*)&Bl[cb][r][s0 * 8] = bv;
        bv[0] = (short)f2bf(pb2.x); bv[1] = (short)f2bf(pb2.y);
        bv[2] = (short)f2bf(pb2.z); bv[3] = (short)f2bf(pb2.w);
        bv[4] = (short)f2bf(pb3.x); bv[5] = (short)f2bf(pb3.y);
        bv[6] = (short)f2bf(pb3.z); bv[7] = (short)f2bf(pb3.w);
        *(bf16x8*)&Bl[cb][r][s0 * 8 + 32] = bv;
        if (t < 7) {
            int ko = (t + 1) * 64;
            pA0 = *(const bf16x8*)(Ag + ko);
            pA1 = *(const bf16x8*)(Ag + ko + 32);
            pb0 = *(const float4*)(Bg + ko);
            pb1 = *(const float4*)(Bg + ko + 4);
            pb2 = *(const float4*)(Bg + ko + 32);
            pb3 = *(const float4*)(Bg + ko + 36);
        }
        if (t > 0) {
            int pb = cb ^ 1;
            bf16x8 af0 = *(const bf16x8*)&Al[pb][wave * 16 + nn][quad * 8];
            bf16x8 af1 = *(const bf16x8*)&Al[pb][wave * 16 + nn][32 + quad * 8];
#pragma unroll
            for (int nt = 0; nt < 4; nt++) {
                bf16x8 b0 = *(const bf16x8*)&Bl[pb][nt * 16 + nn][quad * 8];
                bf16x8 b1 = *(const bf16x8*)&Bl[pb][nt * 16 + nn][32 + quad * 8];
                acc[nt] = __builtin_amdgcn_mfma_f32_16x16x32_bf16(af0, b0, acc[nt], 0, 0, 0);
                acc[nt] = __builtin_amdgcn_mfma_f32_16x16x32_bf16(af1, b1, acc[nt], 0, 0, 0);
            }
        }
        __syncthreads();
    }
    {
        bf16x8 af0 = *(const bf16x8*)&Al[1][wave * 16 + nn][quad * 8];
        bf16x8 af1 = *(const bf16x8*)&Al[1][wave * 16 + nn][32 + quad * 8];
#pragma unroll
        for (int nt = 0; nt < 4; nt++) {
            bf16x8 b0 = *(const bf16x8*)&Bl[1][nt * 16 + nn][quad * 8];
            bf16x8 b1 = *(const bf16x8*)&Bl[1][nt * 16 + nn][32 + quad * 8];
            acc[nt] = __builtin_amdgcn_mfma_f32_16x16x32_bf16(af0, b0, acc[nt], 0, 0, 0);
            acc[nt] = __builtin_amdgcn_mfma_f32_16x16x32_bf16(af1, b1, acc[nt], 0, 0, 0);
        }
    }
    int row0 = mb * 64 + wave * 16 + quad * 4;
    int col0 = nb * 64 + nn;
    int f0i = wave * 16 + quad * 4;
#pragma unroll
    for (int nt = 0; nt < 4; nt++) {
        float s = 0.f, d = 0.f;
#pragma unroll
        for (int rr = 0; rr < 4; rr++) {
            float v = acc[nt][rr];
            WhT[(unsigned)((row0 + rr) * 4096 + col0 + nt * 16)] = f2bf(v);
            s += v * asrc[f0i + rr];
            d += v * adst[f0i + rr];
        }
        s += __shfl_xor(s, 16); s += __shfl_xor(s, 32);
        d += __shfl_xor(d, 16); d += __shfl_xor(d, 32);
        if (quad == 0) { sred[0][wave][nt * 16 + nn] = s; sred[1][wave][nt * 16 + nn] = d; }
    }
    __syncthreads();
    if (tid < 64) {
        float s = sred[0][0][tid] + sred[0][1][tid] + sred[0][2][tid] + sred[0][3][tid];
        unsigned idx = mb * 4096 + nb * 64 + tid;
        expA[idx] = __builtin_amdgcn_exp2f(s);
        expC[idx] = __builtin_amdgcn_exp2f(0.2f * s);
    } else if (tid < 128) {
        int c = tid - 64;
        float d = sred[1][0][c] + sred[1][1][c] + sred[1][2][c] + sred[1][3][c];
        unsigned idx = mb * 4096 + nb * 64 + c;
        expB[idx] = __builtin_amdgcn_exp2f(d);
        expD[idx] = __builtin_amdgcn_exp2f(0.2f * d);
    }
}

// -------- kernel 3: fused attention, j-tile 128, single-buffer Vb, 4 blocks/CU ------
// 512 blocks x 512 thr. wave=(whead, jq); thread gen = A-frags for rows nn and 16+nn
// over j = kb*128 + jq*32 + quad*8 + 0..7. 32 iters, 2 barriers each:
//   gen+denomMFMA -> bar1 -> write Vb -> prefetch -> bar2 -> MFMA cluster.
// Vb[128][136] (272B stride = natural row stagger, proven r13 read pattern).
// Staging remap: vrow=wave*16+(tid&15), vs=(tid>>4)&3 -> 2-way writes per phase.
__global__ __launch_bounds__(512, 8) void gat_attn(const unsigned char* __restrict__ pk,
                                                   const ushort_t* __restrict__ WhT,
                                                   const float* __restrict__ expA,
                                                   const float* __restrict__ expC,
                                                   const float* __restrict__ expB,
                                                   const float* __restrict__ expD,
                                                   float* __restrict__ out) {
    __shared__ __align__(16) ushort_t Vb[128][136];   // 34816 B (cmb overlays)
    __shared__ float denomp[4][2][32];                // 1024 B
    int tid = threadIdx.x;
    int wave = tid >> 6, lane = tid & 63, quad = lane >> 4, nn = lane & 15;
    int hb = blockIdx.x >> 7, ib = blockIdx.x & 127;   // adj row-band on one XCD
    int i0 = ib * 32;
    int whead = wave & 1, jq = wave >> 1;              // jq 0..3
    int g = jq * 4 + quad;
    int head = hb * 2 + whead;
    float Ai0 = expA[head * 4096 + i0 + nn];
    float Ci0 = expC[head * 4096 + i0 + nn];
    float Ai1 = expA[head * 4096 + i0 + 16 + nn];
    float Ci1 = expC[head * 4096 + i0 + 16 + nn];
    const unsigned char* mpA = pk + (unsigned)(i0 + nn) * 512 + g * 32;
    const unsigned char* mpB = mpA + 16 * 512;
    const float* Bp = expB + (unsigned)head * 4096 + jq * 32 + quad * 8;
    const float* Dp = expD + (unsigned)head * 4096 + jq * 32 + quad * 8;
    // V staging: row vrow = wave*16 + (tid&15), col group vs = (tid>>4)&3.
    // Writes at cols vs*8 + s*32 -> per-16-lane-phase banks 2-way (vrow+vs spread).
    int vrow = (wave << 4) | (tid & 15);
    int vs = (tid >> 4) & 3;
    const ushort_t* Vg = WhT + (unsigned)(hb * 128 + vrow) * 4096 + vs * 8;
    bf16x8 onef;
#pragma unroll
    for (int i = 0; i < 8; i++) onef[i] = (short)0x3F80;   // bf16 1.0
    f32x4 acc[2][4] = {};
    f32x4 accd[2] = {};
    bf16x8 pv[4];
    float4 pBD[4];
    pv[0] = *(const bf16x8*)(Vg);
    pv[1] = *(const bf16x8*)(Vg + 32);
    pv[2] = *(const bf16x8*)(Vg + 64);
    pv[3] = *(const bf16x8*)(Vg + 96);
    pBD[0] = *(const float4*)(Bp);
    pBD[1] = *(const float4*)(Bp + 4);
    pBD[2] = *(const float4*)(Dp);
    pBD[3] = *(const float4*)(Dp + 4);
    unsigned mcA = *(const unsigned*)(mpA);
    unsigned mcB = *(const unsigned*)(mpB);
    unsigned mnA = 0, mnB = 0;
    for (int t = 0; t < 8; t++) {
#pragma unroll
        for (int u = 0; u < 4; u++) {
            int kb = t * 4 + u;
            // ---- gen both strips (shared B/D) -- VALU only, no LDS dep ----
            float4 Bv0 = pBD[0], Bv1 = pBD[1], Dv0 = pBD[2], Dv1 = pBD[3];
            bf16x8 af0, af1;
            {
                unsigned w0, w1, w2, w3, w4, w5, w6, w7;
                float w;
                w = fmaxf(Ai0 * Bv0.x, Ci0 * Dv0.x);
                w0 = __builtin_bit_cast(unsigned, w) & 0xFFFF0000u;
                w0 &= (unsigned)__builtin_amdgcn_sbfe(mcA, u * 8 + 0, 1);
                w = fmaxf(Ai0 * Bv0.y, Ci0 * Dv0.y);
                w1 = __builtin_bit_cast(unsigned, w) & 0xFFFF0000u;
                w1 &= (unsigned)__builtin_amdgcn_sbfe(mcA, u * 8 + 1, 1);
                w = fmaxf(Ai0 * Bv0.z, Ci0 * Dv0.z);
                w2 = __builtin_bit_cast(unsigned, w) & 0xFFFF0000u;
                w2 &= (unsigned)__builtin_amdgcn_sbfe(mcA, u * 8 + 2, 1);
                w = fmaxf(Ai0 * Bv0.w, Ci0 * Dv0.w);
                w3 = __builtin_bit_cast(unsigned, w) & 0xFFFF0000u;
                w3 &= (unsigned)__builtin_amdgcn_sbfe(mcA, u * 8 + 3, 1);
                w = fmaxf(Ai0 * Bv1.x, Ci0 * Dv1.x);
                w4 = __builtin_bit_cast(unsigned, w) & 0xFFFF0000u;
                w4 &= (unsigned)__builtin_amdgcn_sbfe(mcA, u * 8 + 4, 1);
                w = fmaxf(Ai0 * Bv1.y, Ci0 * Dv1.y);
                w5 = __builtin_bit_cast(unsigned, w) & 0xFFFF0000u;
                w5 &= (unsigned)__builtin_amdgcn_sbfe(mcA, u * 8 + 5, 1);
                w = fmaxf(Ai0 * Bv1.z, Ci0 * Dv1.z);
                w6 = __builtin_bit_cast(unsigned, w) & 0xFFFF0000u;
                w6 &= (unsigned)__builtin_amdgcn_sbfe(mcA, u * 8 + 6, 1);
                w = fmaxf(Ai0 * Bv1.w, Ci0 * Dv1.w);
                w7 = __builtin_bit_cast(unsigned, w) & 0xFFFF0000u;
                w7 &= (unsigned)__builtin_amdgcn_sbfe(mcA, u * 8 + 7, 1);
                uint4 pq;
                pq.x = __builtin_amdgcn_perm(w1, w0, 0x07060302u);
                pq.y = __builtin_amdgcn_perm(w3, w2, 0x07060302u);
                pq.z = __builtin_amdgcn_perm(w5, w4, 0x07060302u);
                pq.w = __builtin_amdgcn_perm(w7, w6, 0x07060302u);
                af0 = __builtin_bit_cast(bf16x8, pq);
                w = fmaxf(Ai1 * Bv0.x, Ci1 * Dv0.x);
                w0 = __builtin_bit_cast(unsigned, w) & 0xFFFF0000u;
                w0 &= (unsigned)__builtin_amdgcn_sbfe(mcB, u * 8 + 0, 1);
                w = fmaxf(Ai1 * Bv0.y, Ci1 * Dv0.y);
                w1 = __builtin_bit_cast(unsigned, w) & 0xFFFF0000u;
                w1 &= (unsigned)__builtin_amdgcn_sbfe(mcB, u * 8 + 1, 1);
                w = fmaxf(Ai1 * Bv0.z, Ci1 * Dv0.z);
                w2 = __builtin_bit_cast(unsigned, w) & 0xFFFF0000u;
                w2 &= (unsigned)__builtin_amdgcn_sbfe(mcB, u * 8 + 2, 1);
                w = fmaxf(Ai1 * Bv0.w, Ci1 * Dv0.w);
                w3 = __builtin_bit_cast(unsigned, w) & 0xFFFF0000u;
                w3 &= (unsigned)__builtin_amdgcn_sbfe(mcB, u * 8 + 3, 1);
                w = fmaxf(Ai1 * Bv1.x, Ci1 * Dv1.x);
                w4 = __builtin_bit_cast(unsigned, w) & 0xFFFF0000u;
                w4 &= (unsigned)__builtin_amdgcn_sbfe(mcB, u * 8 + 4, 1);
                w = fmaxf(Ai1 * Bv1.y, Ci1 * Dv1.y);
                w5 = __builtin_bit_cast(unsigned, w) & 0xFFFF0000u;
                w5 &= (unsigned)__builtin_amdgcn_sbfe(mcB, u * 8 + 5, 1);
                w = fmaxf(Ai1 * Bv1.z, Ci1 * Dv1.z);
                w6 = __builtin_bit_cast(unsigned, w) & 0xFFFF0000u;
                w6 &= (unsigned)__builtin_amdgcn_sbfe(mcB, u * 8 + 6, 1);
                w = fmaxf(Ai1 * Bv1.w, Ci1 * Dv1.w);
                w7 = __builtin_bit_cast(unsigned, w) & 0xFFFF0000u;
                w7 &= (unsigned)__builtin_amdgcn_sbfe(mcB, u * 8 + 7, 1);
                pq.x = __builtin_amdgcn_perm(w1, w0, 0x07060302u);
                pq.y = __builtin_amdgcn_perm(w3, w2, 0x07060302u);
                pq.z = __builtin_amdgcn_perm(w5, w4, 0x07060302u);
                pq.w = __builtin_amdgcn_perm(w7, w6, 0x07060302u);
                af1 = __builtin_bit_cast(bf16x8, pq);
            }
            if (u == 3) { mcA = mnA; mcB = mnB; }
            // denominator MFMAs: register-only, fill matrix pipe pre-barrier
            accd[0] = __builtin_amdgcn_mfma_f32_16x16x32_bf16(af0, onef, accd[0], 0, 0, 0);
            accd[1] = __builtin_amdgcn_mfma_f32_16x16x32_bf16(af1, onef, accd[1], 0, 0, 0);
            // ---- barrier 1: all reads of tile kb-1 done ----
            __syncthreads();
            // ---- write V tile kb ----
            *(bf16x8*)&Vb[vrow][vs * 8] = pv[0];
            *(bf16x8*)&Vb[vrow][vs * 8 + 32] = pv[1];
            *(bf16x8*)&Vb[vrow][vs * 8 + 64] = pv[2];
            *(bf16x8*)&Vb[vrow][vs * 8 + 96] = pv[3];
            // ---- prefetch tile kb+1 (global -> reg; latency spans bar2+MFMA) ----
            if (kb < 31) {
                const ushort_t* vp = Vg + (kb + 1) * 128;
                pv[0] = *(const bf16x8*)(vp);
                pv[1] = *(const bf16x8*)(vp + 32);
                pv[2] = *(const bf16x8*)(vp + 64);
                pv[3] = *(const bf16x8*)(vp + 96);
                pBD[0] = *(const float4*)(Bp + (kb + 1) * 128);
                pBD[1] = *(const float4*)(Bp + (kb + 1) * 128 + 4);
                pBD[2] = *(const float4*)(Dp + (kb + 1) * 128);
                pBD[3] = *(const float4*)(Dp + (kb + 1) * 128 + 4);
            }
            if (u == 0 && t < 7) {
                mnA = *(const unsigned*)(mpA + (t + 1) * 4);
                mnB = *(const unsigned*)(mpB + (t + 1) * 4);
            }
            // ---- barrier 2: tile kb visible ----
            __syncthreads();
            __builtin_amdgcn_sched_barrier(0);     // pin: prefetch stays above
            // ---- MFMA tile kb: each bv feeds both strips ----
#pragma unroll
            for (int nt = 0; nt < 4; nt++) {
                bf16x8 bv = *(const bf16x8*)&Vb[whead * 64 + nt * 16 + nn][jq * 32 + quad * 8];
                acc[0][nt] = __builtin_amdgcn_mfma_f32_16x16x32_bf16(af0, bv, acc[0][nt], 0, 0, 0);
                acc[1][nt] = __builtin_amdgcn_mfma_f32_16x16x32_bf16(af1, bv, acc[1][nt], 0, 0, 0);
            }
        }
    }
    __syncthreads();   // all Vb reads of tile 31 done before cmb overlay writes
    // denominator partials: row = s*16 + quad*4 + rr
    if (nn == 0) {
#pragma unroll
        for (int s = 0; s < 2; s++)
#pragma unroll
            for (int rr = 0; rr < 4; rr++)
                denomp[jq][whead][s * 16 + quad * 4 + rr] = accd[s][rr];
    }
    // 2-phase combine: cmb overlay on Vb (24576 B <= 34816 B)
    float (*cmb)[3][64][16] = reinterpret_cast<float (*)[3][64][16]>(&Vb[0][0]);
#pragma unroll
    for (int s = 0; s < 2; s++) {
        if (jq > 0) {
#pragma unroll
            for (int nt = 0; nt < 4; nt++)
                *(f32x4*)&cmb[whead][jq - 1][lane][nt * 4] = acc[s][nt];
        }
        __syncthreads();
        if (jq == 0) {
#pragma unroll
            for (int nt = 0; nt < 4; nt++) {
                f32x4 o = acc[s][nt]
                        + *(const f32x4*)&cmb[whead][0][lane][nt * 4]
                        + *(const f32x4*)&cmb[whead][1][lane][nt * 4]
                        + *(const f32x4*)&cmb[whead][2][lane][nt * 4];
#pragma unroll
                for (int rr = 0; rr < 4; rr++) {
                    int il = s * 16 + quad * 4 + rr;
                    float dnm = fmaxf(denomp[0][whead][il] + denomp[1][whead][il]
                                    + denomp[2][whead][il] + denomp[3][whead][il], 1e-30f);
                    float v = o[rr] / dnm;
                    v = v > 0.f ? v : __expf(v) - 1.f;
                    out[(unsigned)(i0 + il) * 512 + hb * 128 + whead * 64 + nt * 16 + nn] = v;
                }
            }
        }
        if (s == 0) __syncthreads();   // jq0 reads done before phase-1 overwrite
    }
}

extern "C" void kernel_launch(void* const* d_in, const int* in_sizes, int n_in,
                              void* d_out, int out_size, void* d_ws, size_t ws_size,
                              hipStream_t stream) {
    const float* h   = (const float*)d_in[0];   // 4096 x 512 fp32
    const int*   adj = (const int*)d_in[1];     // 4096 x 4096 int32
    const float* W   = (const float*)d_in[2];   // 512 x 512 fp32
    const float* a   = (const float*)d_in[3];   // 128 fp32

    char* ws = (char*)d_ws;
    ushort_t* WhT = (ushort_t*)ws;                           // 4 MB
    ushort_t* WT  = (ushort_t*)(ws + (4u << 20));            // 512 KB
    float* expA = (float*)(ws + (4u << 20) + (512u << 10));  // 4 x 128 KB
    float* expC = expA + 8 * 4096;
    float* expB = expC + 8 * 4096;
    float* expD = expB + 8 * 4096;
    unsigned char* pkm = (unsigned char*)(ws + (5u << 20));  // 2 MB bitmask

    transpose_w<<<256, 256, 0, stream>>>(W, WT);
    gemm_pack<<<1536, 256, 0, stream>>>(WT, h, a, WhT, expA, expC, expB, expD,
                                        adj, pkm);
    gat_attn<<<512, 512, 0, stream>>>(pkm, WhT, expA, expC, expB, expD,
                                      (float*)d_out);
}

// Round 4
// 168.035 us; speedup vs baseline: 3.3990x; 3.3990x over previous
//
#include <hip/hip_runtime.h>
#include <hip/hip_bf16.h>

// fp32 inputs (confirmed r2). Internal pipeline bf16 MFMA.
// Gen identity: w = exp2(max(e,0.2e)) = max(A_i*B_j, C_i*D_j).
// r17 = EXACT r13 structure (j-tile 128, double-buffer Vb, 1 barrier/iter,
//   fused pack, proven lane mappings / global coalescing), with ONE change:
//   Vb rows 256B + 4-bit half-swap XOR key on the 16B-granule bits:
//     key(row) = ((row&3)<<2)|((row>>2)&3), phys_byte = logical ^ (key<<4)
//   - write phase: key=(b<<2)|p vs logical granule s0+4s -> 16/16 distinct
//     (r13's 272B layout had 4-way WRITE conflicts = all 8.36M cycles)
//   - read phase: row&15=nn, key bijective over nn -> 16/16 distinct
//     (preserves r13's already-clean reads; r15's (row&7) key broke them)
//   Keys are per-thread constants; global loads unchanged.
//   (r14 no-staging: latency-bound. r15: read conflicts + broken coalescing.
//    r16: launch_bounds(512,8) -> acc spill to scratch, 2.3GB traffic. All reverted.)
// Mask layout: byte pk[i*512 + g*32 + kb] bits r for j = kb*128 + (g>>2)*32 + (g&3)*8 + r.

typedef unsigned short ushort_t;
typedef __attribute__((ext_vector_type(8))) short bf16x8;
typedef __attribute__((ext_vector_type(4))) float f32x4;

#define LOG2E 1.4426950408889634f

__device__ __forceinline__ ushort_t f2bf(float x) {
    unsigned u = __builtin_bit_cast(unsigned, x);
    u += 0x7FFFu + ((u >> 16) & 1u);   // RNE
    return (ushort_t)(u >> 16);
}

// ---------------- kernel 1: WT[c][k] = W[k][c], 512x512, fp32 -> bf16 ----------------
__global__ __launch_bounds__(256) void transpose_w(const float* __restrict__ W,
                                                   ushort_t* __restrict__ WT) {
    __shared__ ushort_t t[32][33];
    int bx = blockIdx.x & 15, by = blockIdx.x >> 4;
    int tx = threadIdx.x & 31, ty = threadIdx.x >> 5;
#pragma unroll
    for (int i = 0; i < 32; i += 8)
        t[ty + i][tx] = f2bf(W[(by * 32 + ty + i) * 512 + bx * 32 + tx]);
    __syncthreads();
#pragma unroll
    for (int i = 0; i < 32; i += 8)
        WT[(bx * 32 + ty + i) * 512 + by * 32 + tx] = t[tx][ty + i];
}

// -------- kernel 2 (fused): blocks 0-511 = gemm (r8 proven body); 512-1535 = pack ----
__global__ __launch_bounds__(256, 4) void gemm_pack(const ushort_t* __restrict__ WT,
                                                    const float* __restrict__ h,
                                                    const float* __restrict__ a,
                                                    ushort_t* __restrict__ WhT,
                                                    float* __restrict__ expA,
                                                    float* __restrict__ expC,
                                                    float* __restrict__ expB,
                                                    float* __restrict__ expD,
                                                    const int* __restrict__ adj,
                                                    unsigned char* __restrict__ pk) {
    __shared__ __align__(16) ushort_t Al[2][64][72];
    __shared__ __align__(16) ushort_t Bl[2][64][72];
    __shared__ float asrc[64], adst[64];
    __shared__ float sred[2][4][64];
    int tid = threadIdx.x;
    if (blockIdx.x >= 512) {
        // ---------------- pack branch ----------------
        int pbid = blockIdx.x - 512;
        int wv = tid >> 6, lane = tid & 63;
        int row = pbid * 4 + wv;
        const int* ap = adj + (unsigned)row * 4096 + lane;
        unsigned char* pp = pk + (unsigned)row * 512;
        int g = lane;                                 // lanes 0..15 write
        int sv = ((g >> 2) & 1) * 4 + (g & 3);
        int cpar = g >> 3;
#pragma unroll 2
        for (int t = 0; t < 8; t++) {
            unsigned long long m[8];
#pragma unroll
            for (int c8 = 0; c8 < 8; c8++)
                m[c8] = __ballot(ap[(t * 8 + c8) * 64] > 0);
            if (lane < 16) {
                unsigned w = 0;
#pragma unroll
                for (int kq = 0; kq < 4; kq++) {
                    unsigned b = (unsigned)(m[2 * kq + cpar] >> (8 * sv)) & 0xFFu;
                    w |= b << (8 * kq);
                }
                *(unsigned*)(pp + g * 32 + t * 4) = w;
            }
        }
        return;
    }
    // ---------------- gemm branch (r8/r12 proven) ----------------
    int wave = tid >> 6, lane = tid & 63, quad = lane >> 4, nn = lane & 15;
    int mb = blockIdx.x & 7, nb = blockIdx.x >> 3;
    if (tid < 64) {
        asrc[tid] = a[tid] * LOG2E;
        adst[tid] = a[64 + tid] * LOG2E;
    }
    int r = tid >> 2, s0 = tid & 3;
    const ushort_t* Ag = WT + (unsigned)((mb * 64 + r) * 512 + s0 * 8);
    const float* Bg = h + (unsigned)((nb * 64 + r) * 512 + s0 * 8);
    bf16x8 pA0 = *(const bf16x8*)(Ag);
    bf16x8 pA1 = *(const bf16x8*)(Ag + 32);
    float4 pb0 = *(const float4*)(Bg);
    float4 pb1 = *(const float4*)(Bg + 4);
    float4 pb2 = *(const float4*)(Bg + 32);
    float4 pb3 = *(const float4*)(Bg + 36);
    f32x4 acc[4] = {};
#pragma unroll 2
    for (int t = 0; t < 8; t++) {
        int cb = t & 1;
        *(bf16x8*)&Al[cb][r][s0 * 8] = pA0;
        *(bf16x8*)&Al[cb][r][s0 * 8 + 32] = pA1;
        bf16x8 bv;
        bv[0] = (short)f2bf(pb0.x); bv[1] = (short)f2bf(pb0.y);
        bv[2] = (short)f2bf(pb0.z); bv[3] = (short)f2bf(pb0.w);
        bv[4] = (short)f2bf(pb1.x); bv[5] = (short)f2bf(pb1.y);
        bv[6] = (short)f2bf(pb1.z); bv[7] = (short)f2bf(pb1.w);
        *(bf16x8*)&Bl[cb][r][s0 * 8] = bv;
        bv[0] = (short)f2bf(pb2.x); bv[1] = (short)f2bf(pb2.y);
        bv[2] = (short)f2bf(pb2.z); bv[3] = (short)f2bf(pb2.w);
        bv[4] = (short)f2bf(pb3.x); bv[5] = (short)f2bf(pb3.y);
        bv[6] = (short)f2bf(pb3.z); bv[7] = (short)f2bf(pb3.w);
        *(bf16x8*)&Bl[cb][r][s0 * 8 + 32] = bv;
        if (t < 7) {
            int ko = (t + 1) * 64;
            pA0 = *(const bf16x8*)(Ag + ko);
            pA1 = *(const bf16x8*)(Ag + ko + 32);
            pb0 = *(const float4*)(Bg + ko);
            pb1 = *(const float4*)(Bg + ko + 4);
            pb2 = *(const float4*)(Bg + ko + 32);
            pb3 = *(const float4*)(Bg + ko + 36);
        }
        if (t > 0) {
            int pb = cb ^ 1;
            bf16x8 af0 = *(const bf16x8*)&Al[pb][wave * 16 + nn][quad * 8];
            bf16x8 af1 = *(const bf16x8*)&Al[pb][wave * 16 + nn][32 + quad * 8];
#pragma unroll
            for (int nt = 0; nt < 4; nt++) {
                bf16x8 b0 = *(const bf16x8*)&Bl[pb][nt * 16 + nn][quad * 8];
                bf16x8 b1 = *(const bf16x8*)&Bl[pb][nt * 16 + nn][32 + quad * 8];
                acc[nt] = __builtin_amdgcn_mfma_f32_16x16x32_bf16(af0, b0, acc[nt], 0, 0, 0);
                acc[nt] = __builtin_amdgcn_mfma_f32_16x16x32_bf16(af1, b1, acc[nt], 0, 0, 0);
            }
        }
        __syncthreads();
    }
    {
        bf16x8 af0 = *(const bf16x8*)&Al[1][wave * 16 + nn][quad * 8];
        bf16x8 af1 = *(const bf16x8*)&Al[1][wave * 16 + nn][32 + quad * 8];
#pragma unroll
        for (int nt = 0; nt < 4; nt++) {
            bf16x8 b0 = *(const bf16x8*)&Bl[1][nt * 16 + nn][quad * 8];
            bf16x8 b1 = *(const bf16x8*)&Bl[1][nt * 16 + nn][32 + quad * 8];
            acc[nt] = __builtin_amdgcn_mfma_f32_16x16x32_bf16(af0, b0, acc[nt], 0, 0, 0);
            acc[nt] = __builtin_amdgcn_mfma_f32_16x16x32_bf16(af1, b1, acc[nt], 0, 0, 0);
        }
    }
    int row0 = mb * 64 + wave * 16 + quad * 4;
    int col0 = nb * 64 + nn;
    int f0i = wave * 16 + quad * 4;
#pragma unroll
    for (int nt = 0; nt < 4; nt++) {
        float s = 0.f, d = 0.f;
#pragma unroll
        for (int rr = 0; rr < 4; rr++) {
            float v = acc[nt][rr];
            WhT[(unsigned)((row0 + rr) * 4096 + col0 + nt * 16)] = f2bf(v);
            s += v * asrc[f0i + rr];
            d += v * adst[f0i + rr];
        }
        s += __shfl_xor(s, 16); s += __shfl_xor(s, 32);
        d += __shfl_xor(d, 16); d += __shfl_xor(d, 32);
        if (quad == 0) { sred[0][wave][nt * 16 + nn] = s; sred[1][wave][nt * 16 + nn] = d; }
    }
    __syncthreads();
    if (tid < 64) {
        float s = sred[0][0][tid] + sred[0][1][tid] + sred[0][2][tid] + sred[0][3][tid];
        unsigned idx = mb * 4096 + nb * 64 + tid;
        expA[idx] = __builtin_amdgcn_exp2f(s);
        expC[idx] = __builtin_amdgcn_exp2f(0.2f * s);
    } else if (tid < 128) {
        int c = tid - 64;
        float d = sred[1][0][c] + sred[1][1][c] + sred[1][2][c] + sred[1][3][c];
        unsigned idx = mb * 4096 + nb * 64 + c;
        expB[idx] = __builtin_amdgcn_exp2f(d);
        expD[idx] = __builtin_amdgcn_exp2f(0.2f * d);
    }
}

// -------- kernel 3: fused attention, j-tile 128, half-swap-XOR swizzled Vb ----------
// 512 blocks x 512 thr (512,4). wave=(whead, jq); thread gen = A-frags for rows
// nn and 16+nn over j = kb*128 + jq*32 + quad*8 + 0..7. 32 iters, 1 barrier each.
// Vb[2][128][128]: element (row, col) at in-row byte (col*2)^(key(row)<<4),
// key(row) = ((row&3)<<2)|((row>>2)&3). Write phase: 16/16 granules distinct.
// Read phase: key bijective over nn -> 16/16 distinct. Keys per-thread constant.
__global__ __launch_bounds__(512, 4) void gat_attn(const unsigned char* __restrict__ pk,
                                                   const ushort_t* __restrict__ WhT,
                                                   const float* __restrict__ expA,
                                                   const float* __restrict__ expC,
                                                   const float* __restrict__ expB,
                                                   const float* __restrict__ expD,
                                                   float* __restrict__ out) {
    __shared__ __align__(16) ushort_t Vb[2][128][128];   // 65536 B (cmb overlays)
    __shared__ float denomp[4][2][32];
    int tid = threadIdx.x;
    int wave = tid >> 6, lane = tid & 63, quad = lane >> 4, nn = lane & 15;
    int hb = blockIdx.x >> 7, ib = blockIdx.x & 127;   // adj row-band on one XCD
    int i0 = ib * 32;
    int whead = wave & 1, jq = wave >> 1;              // jq 0..3
    int g = jq * 4 + quad;
    int head = hb * 2 + whead;
    float Ai0 = expA[head * 4096 + i0 + nn];
    float Ci0 = expC[head * 4096 + i0 + nn];
    float Ai1 = expA[head * 4096 + i0 + 16 + nn];
    float Ci1 = expC[head * 4096 + i0 + 16 + nn];
    const unsigned char* mpA = pk + (unsigned)(i0 + nn) * 512 + g * 32;
    const unsigned char* mpB = mpA + 16 * 512;
    const float* Bp = expB + (unsigned)head * 4096 + jq * 32 + quad * 8;
    const float* Dp = expD + (unsigned)head * 4096 + jq * 32 + quad * 8;
    // V staging: row vrow = tid>>2 (r13 coalesced pattern), col group vs = tid&3.
    int vrow = tid >> 2, vs = tid & 3;
    const ushort_t* Vg = WhT + (unsigned)(hb * 128 + vrow) * 4096 + vs * 8;
    // swizzle keys (per-thread constants)
    int wkey = ((((vrow & 3) << 2) | ((vrow >> 2) & 3)) << 4);
    int wo0 = (vs * 16) ^ wkey;
    int wo1 = (vs * 16 + 64) ^ wkey;
    int wo2 = (vs * 16 + 128) ^ wkey;
    int wo3 = (vs * 16 + 192) ^ wkey;
    int rkey = ((((nn & 3) << 2) | ((nn >> 2) & 3)) << 4);
    int rcol = (jq * 64 + quad * 16) ^ rkey;
    bf16x8 onef;
#pragma unroll
    for (int i = 0; i < 8; i++) onef[i] = (short)0x3F80;   // bf16 1.0
    f32x4 acc[2][4] = {};
    f32x4 accd[2] = {};
    bf16x8 pv[4];
    float4 pBD[4];
    pv[0] = *(const bf16x8*)(Vg);
    pv[1] = *(const bf16x8*)(Vg + 32);
    pv[2] = *(const bf16x8*)(Vg + 64);
    pv[3] = *(const bf16x8*)(Vg + 96);
    pBD[0] = *(const float4*)(Bp);
    pBD[1] = *(const float4*)(Bp + 4);
    pBD[2] = *(const float4*)(Dp);
    pBD[3] = *(const float4*)(Dp + 4);
    unsigned mcA = *(const unsigned*)(mpA);
    unsigned mcB = *(const unsigned*)(mpB);
    unsigned mnA = 0, mnB = 0;
    for (int t = 0; t < 8; t++) {
#pragma unroll
        for (int u = 0; u < 4; u++) {
            int kb = t * 4 + u;
            int cb = kb & 1;
            // ---- store V tile kb (swizzled) ----
            char* vbase = (char*)&Vb[cb][vrow][0];
            *(bf16x8*)(vbase + wo0) = pv[0];
            *(bf16x8*)(vbase + wo1) = pv[1];
            *(bf16x8*)(vbase + wo2) = pv[2];
            *(bf16x8*)(vbase + wo3) = pv[3];
            // ---- gen both strips (shared B/D) ----
            float4 Bv0 = pBD[0], Bv1 = pBD[1], Dv0 = pBD[2], Dv1 = pBD[3];
            bf16x8 af0, af1;
            {
                unsigned w0, w1, w2, w3, w4, w5, w6, w7;
                float w;
                w = fmaxf(Ai0 * Bv0.x, Ci0 * Dv0.x);
                w0 = __builtin_bit_cast(unsigned, w) & 0xFFFF0000u;
                w0 &= (unsigned)__builtin_amdgcn_sbfe(mcA, u * 8 + 0, 1);
                w = fmaxf(Ai0 * Bv0.y, Ci0 * Dv0.y);
                w1 = __builtin_bit_cast(unsigned, w) & 0xFFFF0000u;
                w1 &= (unsigned)__builtin_amdgcn_sbfe(mcA, u * 8 + 1, 1);
                w = fmaxf(Ai0 * Bv0.z, Ci0 * Dv0.z);
                w2 = __builtin_bit_cast(unsigned, w) & 0xFFFF0000u;
                w2 &= (unsigned)__builtin_amdgcn_sbfe(mcA, u * 8 + 2, 1);
                w = fmaxf(Ai0 * Bv0.w, Ci0 * Dv0.w);
                w3 = __builtin_bit_cast(unsigned, w) & 0xFFFF0000u;
                w3 &= (unsigned)__builtin_amdgcn_sbfe(mcA, u * 8 + 3, 1);
                w = fmaxf(Ai0 * Bv1.x, Ci0 * Dv1.x);
                w4 = __builtin_bit_cast(unsigned, w) & 0xFFFF0000u;
                w4 &= (unsigned)__builtin_amdgcn_sbfe(mcA, u * 8 + 4, 1);
                w = fmaxf(Ai0 * Bv1.y, Ci0 * Dv1.y);
                w5 = __builtin_bit_cast(unsigned, w) & 0xFFFF0000u;
                w5 &= (unsigned)__builtin_amdgcn_sbfe(mcA, u * 8 + 5, 1);
                w = fmaxf(Ai0 * Bv1.z, Ci0 * Dv1.z);
                w6 = __builtin_bit_cast(unsigned, w) & 0xFFFF0000u;
                w6 &= (unsigned)__builtin_amdgcn_sbfe(mcA, u * 8 + 6, 1);
                w = fmaxf(Ai0 * Bv1.w, Ci0 * Dv1.w);
                w7 = __builtin_bit_cast(unsigned, w) & 0xFFFF0000u;
                w7 &= (unsigned)__builtin_amdgcn_sbfe(mcA, u * 8 + 7, 1);
                uint4 pq;
                pq.x = __builtin_amdgcn_perm(w1, w0, 0x07060302u);
                pq.y = __builtin_amdgcn_perm(w3, w2, 0x07060302u);
                pq.z = __builtin_amdgcn_perm(w5, w4, 0x07060302u);
                pq.w = __builtin_amdgcn_perm(w7, w6, 0x07060302u);
                af0 = __builtin_bit_cast(bf16x8, pq);
                w = fmaxf(Ai1 * Bv0.x, Ci1 * Dv0.x);
                w0 = __builtin_bit_cast(unsigned, w) & 0xFFFF0000u;
                w0 &= (unsigned)__builtin_amdgcn_sbfe(mcB, u * 8 + 0, 1);
                w = fmaxf(Ai1 * Bv0.y, Ci1 * Dv0.y);
                w1 = __builtin_bit_cast(unsigned, w) & 0xFFFF0000u;
                w1 &= (unsigned)__builtin_amdgcn_sbfe(mcB, u * 8 + 1, 1);
                w = fmaxf(Ai1 * Bv0.z, Ci1 * Dv0.z);
                w2 = __builtin_bit_cast(unsigned, w) & 0xFFFF0000u;
                w2 &= (unsigned)__builtin_amdgcn_sbfe(mcB, u * 8 + 2, 1);
                w = fmaxf(Ai1 * Bv0.w, Ci1 * Dv0.w);
                w3 = __builtin_bit_cast(unsigned, w) & 0xFFFF0000u;
                w3 &= (unsigned)__builtin_amdgcn_sbfe(mcB, u * 8 + 3, 1);
                w = fmaxf(Ai1 * Bv1.x, Ci1 * Dv1.x);
                w4 = __builtin_bit_cast(unsigned, w) & 0xFFFF0000u;
                w4 &= (unsigned)__builtin_amdgcn_sbfe(mcB, u * 8 + 4, 1);
                w = fmaxf(Ai1 * Bv1.y, Ci1 * Dv1.y);
                w5 = __builtin_bit_cast(unsigned, w) & 0xFFFF0000u;
                w5 &= (unsigned)__builtin_amdgcn_sbfe(mcB, u * 8 + 5, 1);
                w = fmaxf(Ai1 * Bv1.z, Ci1 * Dv1.z);
                w6 = __builtin_bit_cast(unsigned, w) & 0xFFFF0000u;
                w6 &= (unsigned)__builtin_amdgcn_sbfe(mcB, u * 8 + 6, 1);
                w = fmaxf(Ai1 * Bv1.w, Ci1 * Dv1.w);
                w7 = __builtin_bit_cast(unsigned, w) & 0xFFFF0000u;
                w7 &= (unsigned)__builtin_amdgcn_sbfe(mcB, u * 8 + 7, 1);
                pq.x = __builtin_amdgcn_perm(w1, w0, 0x07060302u);
                pq.y = __builtin_amdgcn_perm(w3, w2, 0x07060302u);
                pq.z = __builtin_amdgcn_perm(w5, w4, 0x07060302u);
                pq.w = __builtin_amdgcn_perm(w7, w6, 0x07060302u);
                af1 = __builtin_bit_cast(bf16x8, pq);
            }
            if (u == 3) { mcA = mnA; mcB = mnB; }
            __syncthreads();                       // drains only iter-old loads
            __builtin_amdgcn_sched_barrier(0);     // pin: loads below stay below
            // ---- prefetch tile kb+1 ----
            if (kb < 31) {
                const ushort_t* vp = Vg + (kb + 1) * 128;
                pv[0] = *(const bf16x8*)(vp);
                pv[1] = *(const bf16x8*)(vp + 32);
                pv[2] = *(const bf16x8*)(vp + 64);
                pv[3] = *(const bf16x8*)(vp + 96);
                pBD[0] = *(const float4*)(Bp + (kb + 1) * 128);
                pBD[1] = *(const float4*)(Bp + (kb + 1) * 128 + 4);
                pBD[2] = *(const float4*)(Dp + (kb + 1) * 128);
                pBD[3] = *(const float4*)(Dp + (kb + 1) * 128 + 4);
            }
            if (u == 0 && t < 7) {
                mnA = *(const unsigned*)(mpA + (t + 1) * 4);
                mnB = *(const unsigned*)(mpB + (t + 1) * 4);
            }
            // ---- MFMA tile kb: each bv feeds both strips ----
#pragma unroll
            for (int nt = 0; nt < 4; nt++) {
                bf16x8 bv = *(const bf16x8*)((const char*)&Vb[cb][whead * 64 + nt * 16 + nn][0] + rcol);
                acc[0][nt] = __builtin_amdgcn_mfma_f32_16x16x32_bf16(af0, bv, acc[0][nt], 0, 0, 0);
                acc[1][nt] = __builtin_amdgcn_mfma_f32_16x16x32_bf16(af1, bv, acc[1][nt], 0, 0, 0);
            }
            accd[0] = __builtin_amdgcn_mfma_f32_16x16x32_bf16(af0, onef, accd[0], 0, 0, 0);
            accd[1] = __builtin_amdgcn_mfma_f32_16x16x32_bf16(af1, onef, accd[1], 0, 0, 0);
        }
    }
    __syncthreads();   // all Vb reads of tile 31 done before cmb overlay writes
    // denominator partials: row = s*16 + quad*4 + rr
    if (nn == 0) {
#pragma unroll
        for (int s = 0; s < 2; s++)
#pragma unroll
            for (int rr = 0; rr < 4; rr++)
                denomp[jq][whead][s * 16 + quad * 4 + rr] = accd[s][rr];
    }
    // combine jq partials via cmb overlay on Vb (49152 B <= 65536 B)
    float (*cmb)[3][64][32] = reinterpret_cast<float (*)[3][64][32]>(&Vb[0][0][0]);
    if (jq > 0) {
#pragma unroll
        for (int s = 0; s < 2; s++)
#pragma unroll
            for (int nt = 0; nt < 4; nt++)
                *(f32x4*)&cmb[whead][jq - 1][lane][s * 16 + nt * 4] = acc[s][nt];
    }
    __syncthreads();
    if (jq == 0) {
#pragma unroll
        for (int s = 0; s < 2; s++) {
#pragma unroll
            for (int nt = 0; nt < 4; nt++) {
                f32x4 o = acc[s][nt]
                        + *(const f32x4*)&cmb[whead][0][lane][s * 16 + nt * 4]
                        + *(const f32x4*)&cmb[whead][1][lane][s * 16 + nt * 4]
                        + *(const f32x4*)&cmb[whead][2][lane][s * 16 + nt * 4];
#pragma unroll
                for (int rr = 0; rr < 4; rr++) {
                    int il = s * 16 + quad * 4 + rr;
                    float dnm = fmaxf(denomp[0][whead][il] + denomp[1][whead][il]
                                    + denomp[2][whead][il] + denomp[3][whead][il], 1e-30f);
                    float v = o[rr] / dnm;
                    v = v > 0.f ? v : __expf(v) - 1.f;
                    out[(unsigned)(i0 + il) * 512 + hb * 128 + whead * 64 + nt * 16 + nn] = v;
                }
            }
        }
    }
}

extern "C" void kernel_launch(void* const* d_in, const int* in_sizes, int n_in,
                              void* d_out, int out_size, void* d_ws, size_t ws_size,
                              hipStream_t stream) {
    const float* h   = (const float*)d_in[0];   // 4096 x 512 fp32
    const int*   adj = (const int*)d_in[1];     // 4096 x 4096 int32
    const float* W   = (const float*)d_in[2];   // 512 x 512 fp32
    const float* a   = (const float*)d_in[3];   // 128 fp32

    char* ws = (char*)d_ws;
    ushort_t* WhT = (ushort_t*)ws;                           // 4 MB
    ushort_t* WT  = (ushort_t*)(ws + (4u << 20));            // 512 KB
    float* expA = (float*)(ws + (4u << 20) + (512u << 10));  // 4 x 128 KB
    float* expC = expA + 8 * 4096;
    float* expB = expC + 8 * 4096;
    float* expD = expB + 8 * 4096;
    unsigned char* pkm = (unsigned char*)(ws + (5u << 20));  // 2 MB bitmask

    transpose_w<<<256, 256, 0, stream>>>(W, WT);
    gemm_pack<<<1536, 256, 0, stream>>>(WT, h, a, WhT, expA, expC, expB, expD,
                                        adj, pkm);
    gat_attn<<<512, 512, 0, stream>>>(pkm, WhT, expA, expC, expB, expD,
                                      (float*)d_out);
}